// Round 5
// baseline (180.129 us; speedup 1.0000x reference)
//
#include <hip/hip_runtime.h>

// Causal self-attention fwd: B=2,T=2048,C=1024,H=16,D=64, scale=0.1/sqrt(D)
// prep (cast x + transpose weights); qkv GEMM 128x128 BK=64 (global_load_lds,
// XOR seg swizzle, q pre-scaled by SCALE*log2e, V written PRE-TRANSPOSED to
// vT[d][s]); flash attn (S^T = K*Q^T, P in registers as 16x16x16-MFMA
// A-frags; K AND V staged via global_load_lds w/ global-side XOR swizzle --
// zero DS-write staging; double-buffered, 1 barrier/stage; m=0 softmax;
// XCD-affine CU-balanced grid); proj GEMM now 128x128 (R5: TN=64 -> TN=128,
// halves A-panel refetch + staging-per-output; same proven m97 template).
// R2-R4 lesson: 256^2 8-phase qkv (3 variants) never beat this 128^2
// structure at K=1024/16 K-tiles -- reverted per kill-switch.

#define Bz 2
#define Tz 2048
#define Cz 1024
#define Hz 16
#define Dz 64
// SCALE * log2(e): q pre-scaled so attn does p = exp2(S) directly
#define QSCALE 0.01803368801111437f

typedef unsigned short u16;
typedef short bf16x4 __attribute__((ext_vector_type(4)));
typedef short bf16x8 __attribute__((ext_vector_type(8)));
typedef float f32x4 __attribute__((ext_vector_type(4)));

#define MFMA32(A, B, C) __builtin_amdgcn_mfma_f32_16x16x32_bf16(A, B, C, 0, 0, 0)

// K=16 bf16 MFMA. Guard with __HIP_DEVICE_COMPILE__ (R8 lesson: __has_builtin
// is unreliable for aux-target builtins in the host pass).
__device__ inline f32x4 mfma16(bf16x4 a, bf16x4 b, f32x4 c) {
#if defined(__HIP_DEVICE_COMPILE__)
  return __builtin_amdgcn_mfma_f32_16x16x16bf16_1k(a, b, c, 0, 0, 0);
#else
  return c;  // host pass placeholder, never executed
#endif
}

__device__ inline u16 f2bf(float f) {  // round-half-up: 2 VALU, <=0.5 ulp
  return (u16)((__float_as_uint(f) + 0x8000u) >> 16);
}

__device__ inline float fexp2(float x) {  // raw v_exp_f32 (R6-proven guard)
#if __has_builtin(__builtin_amdgcn_exp2f)
  return __builtin_amdgcn_exp2f(x);
#else
  return exp2f(x);
#endif
}

__device__ inline void gl_lds16(const u16* g, u16* l) {
  __builtin_amdgcn_global_load_lds(
      (const __attribute__((address_space(1))) void*)g,
      (__attribute__((address_space(3))) void*)l, 16, 0, 0);
}

// ------------- prep: cast x->bf16 + transpose/cast both weights -------------
#define NCAST 4096   // (4096*1024/4)/256
#define NTA   3072   // (3072/32)*(1024/32)
__global__ __launch_bounds__(256) void prep_kernel(const float* __restrict__ x,
                                                   const float* __restrict__ wa,
                                                   const float* __restrict__ wp,
                                                   u16* __restrict__ xb,
                                                   u16* __restrict__ waT,
                                                   u16* __restrict__ wpT) {
  const int bx = blockIdx.x, t = threadIdx.x;
  if (bx < NCAST) {
    int i = bx * 256 + t;
    float4 v = ((const float4*)x)[i];
    ushort4 o = {f2bf(v.x), f2bf(v.y), f2bf(v.z), f2bf(v.w)};
    ((ushort4*)xb)[i] = o;
    return;
  }
  __shared__ float tile[32][33];
  const float* W;
  u16* WT;
  int N, idx;
  if (bx < NCAST + NTA) {
    W = wa; WT = waT; N = 3 * Cz; idx = bx - NCAST;
  } else {
    W = wp; WT = wpT; N = Cz; idx = bx - NCAST - NTA;
  }
  const int n0 = (idx % (N / 32)) * 32, k0 = (idx / (N / 32)) * 32;
  const int tx = t & 31, ty = t >> 5;  // (32, 8)
#pragma unroll
  for (int i = 0; i < 4; ++i)
    tile[ty + 8 * i][tx] = W[(size_t)(k0 + ty + 8 * i) * N + n0 + tx];
  __syncthreads();
#pragma unroll
  for (int i = 0; i < 4; ++i)
    WT[(size_t)(n0 + ty + 8 * i) * Cz + k0 + tx] = f2bf(tile[tx][ty + 8 * i]);
}

// ---------- C[M][N] = A[M][K]*BT[N][K]^T + bias; 128xTN tile, BK=64 ----------
// VSPLIT: cols >= 2C are V -- written transposed to vTout[(b*1024 + (gc-2C))]
// [s] as ushort4 (lane's 4 consecutive s), skipping Cout.
template <bool OUT_BF16, int TN, bool VSPLIT>
__global__ __launch_bounds__(256) void gemm_bt(const u16* __restrict__ A,
                                               const u16* __restrict__ BT,
                                               const float* __restrict__ bias,
                                               void* __restrict__ Cout,
                                               u16* __restrict__ vTout,
                                               int M, int N, int K,
                                               int qcols, float qscale) {
  __shared__ __align__(16) u16 As[128 * 64];
  __shared__ __align__(16) u16 Bs[TN * 64];
  constexpr int NT = TN / 32;
  const int t = threadIdx.x;
  const int wave = t >> 6, lane = t & 63;
  const int lm = lane & 15, lg = lane >> 4;
  const int wm = wave >> 1, wn = wave & 1;
  const int m0 = blockIdx.y * 128, n0 = blockIdx.x * TN;

  const int lrow = lane >> 3;                 // 0..7
  const int gseg = (lane & 7) ^ lrow;         // global col-seg (XOR swizzle)
  const size_t a_base = (size_t)(m0 + 32 * wave + lrow) * K + gseg * 8;
  u16* const a_lds = &As[(32 * wave) * 64];
  const size_t b_base = (size_t)(n0 + (TN / 4) * wave + lrow) * K + gseg * 8;
  u16* const b_lds = &Bs[((TN / 4) * wave) * 64];

  f32x4 acc[4][NT];
#pragma unroll
  for (int mt = 0; mt < 4; ++mt)
#pragma unroll
    for (int nt = 0; nt < NT; ++nt)
#pragma unroll
      for (int i = 0; i < 4; ++i) acc[mt][nt][i] = 0.f;

  for (int k0 = 0; k0 < K; k0 += 64) {
    __syncthreads();
#pragma unroll
    for (int i = 0; i < 4; ++i)
      gl_lds16(A + a_base + (size_t)(8 * i) * K + k0, a_lds + i * 8 * 64);
#pragma unroll
    for (int i = 0; i < NT; ++i)
      gl_lds16(BT + b_base + (size_t)(8 * i) * K + k0, b_lds + i * 8 * 64);
    __syncthreads();

#pragma unroll
    for (int h = 0; h < 2; ++h) {
      const int rs = ((lg + 4 * h) ^ (lm & 7)) * 8;
      bf16x8 af[4], bfr[NT];
#pragma unroll
      for (int mt = 0; mt < 4; ++mt)
        af[mt] = *(const bf16x8*)&As[(64 * wm + 16 * mt + lm) * 64 + rs];
#pragma unroll
      for (int nt = 0; nt < NT; ++nt)
        bfr[nt] = *(const bf16x8*)&Bs[((TN / 2) * wn + 16 * nt + lm) * 64 + rs];
#pragma unroll
      for (int mt = 0; mt < 4; ++mt)
#pragma unroll
        for (int nt = 0; nt < NT; ++nt)
          acc[mt][nt] = MFMA32(af[mt], bfr[nt], acc[mt][nt]);
    }
  }

#pragma unroll
  for (int nt = 0; nt < NT; ++nt) {
    int gc = n0 + (TN / 2) * wn + 16 * nt + lm;
    float bv = bias[gc];
    if (VSPLIT && gc >= 2 * Cz) {
      // V column -> transposed store: vTout[(b*1024 + dg)][s0..s0+3]
      const int dg = gc - 2 * Cz;
#pragma unroll
      for (int mt = 0; mt < 4; ++mt) {
        const int gr0 = m0 + 64 * wm + 16 * mt + 4 * lg;
        const int bb = gr0 >> 11, s0 = gr0 & 2047;
        ushort4 o = {f2bf(acc[mt][nt][0] + bv), f2bf(acc[mt][nt][1] + bv),
                     f2bf(acc[mt][nt][2] + bv), f2bf(acc[mt][nt][3] + bv)};
        *(ushort4*)(vTout + (((size_t)(bb * 1024 + dg)) << 11) + s0) = o;
      }
      continue;
    }
    float sc = (gc < qcols) ? qscale : 1.f;
#pragma unroll
    for (int mt = 0; mt < 4; ++mt) {
#pragma unroll
      for (int i = 0; i < 4; ++i) {
        int gr = m0 + 64 * wm + 16 * mt + 4 * lg + i;
        float v = (acc[mt][nt][i] + bv) * sc;
        if (OUT_BF16)
          ((u16*)Cout)[(size_t)gr * N + gc] = f2bf(v);
        else
          ((float*)Cout)[(size_t)gr * N + gc] = v;
      }
    }
  }
}

// ---------------- flash attention, MFMA bf16, m=0 softmax, S^T ----------------
// 1D grid 1024: x = qtp*32+bh (XCD-affine); balanced qt = qtp<16?qtp:47-qtp.
// Wave w owns Q-rows [64qt+16w,+16). S^T = K*Q^T; p = exp2(S^T) packed
// in-register as 16x16x16-MFMA A-frag (P never touches LDS). K and V staged
// with global_load_lds (w=16) into unpadded stride-64 LDS; conflicts killed
// by XOR swizzle on the GLOBAL address (seg_g = seg_l ^ (row&7)) -- legal
// since gl_lds global addrs are per-lane, LDS base wave-uniform (m104).
// Frag reads un-swizzle; K b128 and V b64 patterns are bank-minimal (free).
// Double-buffered, ONE barrier/stage; gl_lds for kt+1 issued right after the
// barrier. V comes from pre-transposed vT[d][s] (written by qkv GEMM).
__global__ __launch_bounds__(256) void attn_kernel(const u16* __restrict__ qkv,
                                                   const u16* __restrict__ vT,
                                                   u16* __restrict__ yb) {
  __shared__ __align__(16) u16 KsL[2][64 * 64];
  __shared__ __align__(16) u16 VtL[2][64 * 64];

  const int t = threadIdx.x;
  const int wave = t >> 6, lane = t & 63;
  const int lm = lane & 15, lg = lane >> 4;
  const int x = blockIdx.x;
  const int bh = x & 31, qtp = x >> 5;
  const int qt = (qtp < 16) ? qtp : 47 - qtp;  // CU-balanced map
  const int b = bh >> 4, h = bh & 15;
  const int q0 = qt * 64;
  const size_t rowstride = 3 * Cz;
  const u16* qbase = qkv + (size_t)b * Tz * rowstride + h * Dz;
  const u16* vTbh = vT + ((size_t)(b * Hz + h) * Dz) * Tz;  // [64][2048]

  // Q fragments: B-operand of the S^T MFMA (lane lm = q-col, elems = d)
  bf16x8 qf[2];
  {
    const u16* qrow = qbase + (size_t)(q0 + wave * 16 + lm) * rowstride + (lg << 3);
    qf[0] = *(const bf16x8*)qrow;
    qf[1] = *(const bf16x8*)(qrow + 32);
  }

  float psum = 0.f;  // l for q = 16*wave + lm (partial over this lane's s)
  f32x4 Oa[4];       // Oa[dt][r] = O[q=16w+4lg+r][d=16dt+lm]
#pragma unroll
  for (int i = 0; i < 4; ++i)
#pragma unroll
    for (int j = 0; j < 4; ++j) Oa[i][j] = 0.f;

  // staging: wave w stages rows [16w,16w+16) of both K and V tiles.
  // lane i -> row +(i>>3), LDS seg i&7 holding GLOBAL seg (i&7)^(i>>3).
  const int srow = lane >> 3;              // 0..7
  const int sgl = ((lane & 7) ^ srow) * 8; // global col offset (swizzled)
  const u16* kstg = qbase + Cz + (size_t)(16 * wave + srow) * rowstride + sgl;
  const u16* vstg = vTbh + (size_t)(16 * wave + srow) * Tz + sgl;

  auto stage_issue = [&](int kt, int buf) {
#pragma unroll
    for (int c2 = 0; c2 < 2; ++c2) {
      gl_lds16(kstg + (size_t)(8 * c2) * rowstride + (size_t)(64 * kt) * rowstride,
               &KsL[buf][(16 * wave + 8 * c2) * 64]);
      gl_lds16(vstg + (size_t)(8 * c2) * Tz + 64 * kt,
               &VtL[buf][(16 * wave + 8 * c2) * 64]);
    }
  };

  stage_issue(0, 0);  // prologue; first barrier drains it

  for (int kt = 0; kt <= qt; ++kt) {
    __syncthreads();  // buf(kt&1) loads drained; prior readers of other buf done
    const int cb = kt & 1;
    if (kt + 1 <= qt) stage_issue(kt + 1, 1 - cb);

    // ---- S^T = K Q^T (pre-scaled): lane gets s=16c+4lg+r, q=16w+lm ----
    f32x4 S[4];
#pragma unroll
    for (int c = 0; c < 4; ++c) {
      const int rb = (16 * c + lm) * 64;
      bf16x8 k0 = *(const bf16x8*)&KsL[cb][rb + ((lg ^ (lm & 7)) << 3)];
      bf16x8 k1 = *(const bf16x8*)&KsL[cb][rb + (((lg + 4) ^ (lm & 7)) << 3)];
      f32x4 s;
#pragma unroll
      for (int i = 0; i < 4; ++i) s[i] = 0.f;
      s = MFMA32(k0, qf[0], s);
      s = MFMA32(k1, qf[1], s);
      S[c] = s;
    }

    // ---- p = exp2(S^T), diag mask, accumulate l, pack A-frags in-reg ----
    const bool diag = (kt == qt);
    const int qloc = 16 * wave + lm;
    bf16x4 pf[4];
#pragma unroll
    for (int c = 0; c < 4; ++c) {
#pragma unroll
      for (int r = 0; r < 4; ++r) {
        float p = fexp2(S[c][r]);
        if (diag && (c * 16 + 4 * lg + r) > qloc) p = 0.f;
        psum += p;
        pf[c][r] = (short)f2bf(p);
      }
    }

    // ---- O += P V: K=16 MFMAs, A=pf (registers), B from VtL[d][s] ----
#pragma unroll
    for (int dt = 0; dt < 4; ++dt) {
      const int rb = (16 * dt + lm) * 64;
#pragma unroll
      for (int c = 0; c < 4; ++c) {
        const int off = (((2 * c + (lg >> 1)) ^ (lm & 7)) << 3) + 4 * (lg & 1);
        bf16x4 vfr = *(const bf16x4*)&VtL[cb][rb + off];
        Oa[dt] = mfma16(pf[c], vfr, Oa[dt]);
      }
    }
  }

  // ---- epilogue: l-reduce over lg, redistribute inv, bounce via KsL[0] ----
  float s = psum;
  s += __shfl_xor(s, 16);
  s += __shfl_xor(s, 32);
  const float linv = 1.f / s;  // l(q=16w+lm), valid at all lg
  float invq[4];
#pragma unroll
  for (int r = 0; r < 4; ++r)
    invq[r] = __shfl(linv, 20 * lg + r);  // lane with lm = 4lg+r (same lg)
  __syncthreads();  // all KsL/VtL readers done; reuse KsL[0] as store bounce
#pragma unroll
  for (int dt = 0; dt < 4; ++dt)
#pragma unroll
    for (int r = 0; r < 4; ++r)
      KsL[0][(16 * wave + 4 * lg + r) * 64 + 16 * dt + lm] =
          f2bf(Oa[dt][r] * invq[r]);
  __syncthreads();
  {
    const int row = lane >> 2, seg = lane & 3;
    const uint4* src = (const uint4*)&KsL[0][(16 * wave + row) * 64 + seg * 16];
    uint4 v0 = src[0];
    uint4 v1 = src[1];
    u16* dst = yb + (size_t)(b * Tz + q0 + 16 * wave + row) * Cz + h * Dz + seg * 16;
    *(uint4*)dst = v0;
    *(uint4*)(dst + 8) = v1;
  }
}

extern "C" void kernel_launch(void* const* d_in, const int* in_sizes, int n_in,
                              void* d_out, int out_size, void* d_ws, size_t ws_size,
                              hipStream_t stream) {
  const float* x      = (const float*)d_in[0];
  const float* w_attn = (const float*)d_in[1];
  const float* b_attn = (const float*)d_in[2];
  const float* w_proj = (const float*)d_in[3];
  const float* b_proj = (const float*)d_in[4];

  char* ws = (char*)d_ws;
  u16* xb   = (u16*)(ws);                        //  8 MB: x bf16 [4096,1024]
  u16* waT  = (u16*)(ws + (8ull << 20));         //  6 MB: w_attn^T bf16 [3072,1024]
  u16* wpT  = (u16*)(ws + (14ull << 20));        //  2 MB: w_proj^T bf16 [1024,1024]
  u16* qkvb = (u16*)(ws + (16ull << 20));        // 24 MB: qkv bf16 (q pre-scaled; V cols unused)
  u16* yb   = (u16*)(ws + (40ull << 20));        //  8 MB: y bf16 [4096,1024]
  u16* vTt  = (u16*)(ws + (48ull << 20));        //  8 MB: V^T bf16 [2*16*64][2048]

  const int M = Bz * Tz;  // 4096

  prep_kernel<<<NCAST + NTA + 1024, 256, 0, stream>>>(x, w_attn, w_proj, xb, waT, wpT);
  gemm_bt<true, 128, true><<<dim3(3 * Cz / 128, M / 128), 256, 0, stream>>>(
      xb, waT, b_attn, qkvb, vTt, M, 3 * Cz, Cz, Cz, QSCALE);
  attn_kernel<<<1024, 256, 0, stream>>>(qkvb, vTt, yb);
  gemm_bt<false, 128, false><<<dim3(Cz / 128, M / 128), 256, 0, stream>>>(
      yb, wpT, b_proj, d_out, nullptr, M, Cz, Cz, 0, 1.f);
}

// Round 6
// 174.487 us; speedup vs baseline: 1.0323x; 1.0323x over previous
//
#include <hip/hip_runtime.h>

// Causal self-attention fwd: B=2,T=2048,C=1024,H=16,D=64, scale=0.1/sqrt(D)
// prep (cast x + transpose weights); qkv GEMM 128x96 BK=64 (R6: TN=128->96,
// grid 768->1024 blocks = 4 blocks/CU, occupancy was grid-limited;
// global_load_lds, XOR seg swizzle, q pre-scaled by SCALE*log2e, V written
// PRE-TRANSPOSED to vT[d][s]); flash attn (S^T = K*Q^T, P in registers as
// 16x16x16-MFMA A-frags; K AND V staged via global_load_lds w/ global-side
// XOR swizzle; double-buffered, 1 barrier/stage; m=0 softmax; XCD-affine
// CU-balanced grid); proj GEMM 128x64 (R5 lesson: TN=128 -> 1 block/CU
// regressed ~9.5us; TN=64 = 2 blocks/CU is the proven point).
// R2-R4 lesson: 256^2 8-phase qkv (3 variants) never beat this 128-row
// structure at K=1024/16 K-tiles -- closed.

#define Bz 2
#define Tz 2048
#define Cz 1024
#define Hz 16
#define Dz 64
// SCALE * log2(e): q pre-scaled so attn does p = exp2(S) directly
#define QSCALE 0.01803368801111437f

typedef unsigned short u16;
typedef short bf16x4 __attribute__((ext_vector_type(4)));
typedef short bf16x8 __attribute__((ext_vector_type(8)));
typedef float f32x4 __attribute__((ext_vector_type(4)));

#define MFMA32(A, B, C) __builtin_amdgcn_mfma_f32_16x16x32_bf16(A, B, C, 0, 0, 0)

// K=16 bf16 MFMA. Guard with __HIP_DEVICE_COMPILE__ (R8 lesson: __has_builtin
// is unreliable for aux-target builtins in the host pass).
__device__ inline f32x4 mfma16(bf16x4 a, bf16x4 b, f32x4 c) {
#if defined(__HIP_DEVICE_COMPILE__)
  return __builtin_amdgcn_mfma_f32_16x16x16bf16_1k(a, b, c, 0, 0, 0);
#else
  return c;  // host pass placeholder, never executed
#endif
}

__device__ inline u16 f2bf(float f) {  // round-half-up: 2 VALU, <=0.5 ulp
  return (u16)((__float_as_uint(f) + 0x8000u) >> 16);
}

__device__ inline float fexp2(float x) {  // raw v_exp_f32 (R6-proven guard)
#if __has_builtin(__builtin_amdgcn_exp2f)
  return __builtin_amdgcn_exp2f(x);
#else
  return exp2f(x);
#endif
}

__device__ inline void gl_lds16(const u16* g, u16* l) {
  __builtin_amdgcn_global_load_lds(
      (const __attribute__((address_space(1))) void*)g,
      (__attribute__((address_space(3))) void*)l, 16, 0, 0);
}

// ------------- prep: cast x->bf16 + transpose/cast both weights -------------
#define NCAST 4096   // (4096*1024/4)/256
#define NTA   3072   // (3072/32)*(1024/32)
__global__ __launch_bounds__(256) void prep_kernel(const float* __restrict__ x,
                                                   const float* __restrict__ wa,
                                                   const float* __restrict__ wp,
                                                   u16* __restrict__ xb,
                                                   u16* __restrict__ waT,
                                                   u16* __restrict__ wpT) {
  const int bx = blockIdx.x, t = threadIdx.x;
  if (bx < NCAST) {
    int i = bx * 256 + t;
    float4 v = ((const float4*)x)[i];
    ushort4 o = {f2bf(v.x), f2bf(v.y), f2bf(v.z), f2bf(v.w)};
    ((ushort4*)xb)[i] = o;
    return;
  }
  __shared__ float tile[32][33];
  const float* W;
  u16* WT;
  int N, idx;
  if (bx < NCAST + NTA) {
    W = wa; WT = waT; N = 3 * Cz; idx = bx - NCAST;
  } else {
    W = wp; WT = wpT; N = Cz; idx = bx - NCAST - NTA;
  }
  const int n0 = (idx % (N / 32)) * 32, k0 = (idx / (N / 32)) * 32;
  const int tx = t & 31, ty = t >> 5;  // (32, 8)
#pragma unroll
  for (int i = 0; i < 4; ++i)
    tile[ty + 8 * i][tx] = W[(size_t)(k0 + ty + 8 * i) * N + n0 + tx];
  __syncthreads();
#pragma unroll
  for (int i = 0; i < 4; ++i)
    WT[(size_t)(n0 + ty + 8 * i) * Cz + k0 + tx] = f2bf(tile[tx][ty + 8 * i]);
}

// ---------- C[M][N] = A[M][K]*BT[N][K]^T + bias; 128xTN tile, BK=64 ----------
// VSPLIT: cols >= 2C are V -- written transposed to vTout[(b*1024 + (gc-2C))]
// [s] as ushort4 (lane's 4 consecutive s), skipping Cout.  All q/k/V and
// qscale handling is PER-COLUMN (gc), so tiles may straddle the boundaries
// (needed for TN=96).
template <bool OUT_BF16, int TN, bool VSPLIT>
__global__ __launch_bounds__(256) void gemm_bt(const u16* __restrict__ A,
                                               const u16* __restrict__ BT,
                                               const float* __restrict__ bias,
                                               void* __restrict__ Cout,
                                               u16* __restrict__ vTout,
                                               int M, int N, int K,
                                               int qcols, float qscale) {
  __shared__ __align__(16) u16 As[128 * 64];
  __shared__ __align__(16) u16 Bs[TN * 64];
  constexpr int NT = TN / 32;
  const int t = threadIdx.x;
  const int wave = t >> 6, lane = t & 63;
  const int lm = lane & 15, lg = lane >> 4;
  const int wm = wave >> 1, wn = wave & 1;
  const int m0 = blockIdx.y * 128, n0 = blockIdx.x * TN;

  const int lrow = lane >> 3;                 // 0..7
  const int gseg = (lane & 7) ^ lrow;         // global col-seg (XOR swizzle)
  const size_t a_base = (size_t)(m0 + 32 * wave + lrow) * K + gseg * 8;
  u16* const a_lds = &As[(32 * wave) * 64];
  const size_t b_base = (size_t)(n0 + (TN / 4) * wave + lrow) * K + gseg * 8;
  u16* const b_lds = &Bs[((TN / 4) * wave) * 64];

  f32x4 acc[4][NT];
#pragma unroll
  for (int mt = 0; mt < 4; ++mt)
#pragma unroll
    for (int nt = 0; nt < NT; ++nt)
#pragma unroll
      for (int i = 0; i < 4; ++i) acc[mt][nt][i] = 0.f;

  for (int k0 = 0; k0 < K; k0 += 64) {
    __syncthreads();
#pragma unroll
    for (int i = 0; i < 4; ++i)
      gl_lds16(A + a_base + (size_t)(8 * i) * K + k0, a_lds + i * 8 * 64);
#pragma unroll
    for (int i = 0; i < NT; ++i)
      gl_lds16(BT + b_base + (size_t)(8 * i) * K + k0, b_lds + i * 8 * 64);
    __syncthreads();

#pragma unroll
    for (int h = 0; h < 2; ++h) {
      const int rs = ((lg + 4 * h) ^ (lm & 7)) * 8;
      bf16x8 af[4], bfr[NT];
#pragma unroll
      for (int mt = 0; mt < 4; ++mt)
        af[mt] = *(const bf16x8*)&As[(64 * wm + 16 * mt + lm) * 64 + rs];
#pragma unroll
      for (int nt = 0; nt < NT; ++nt)
        bfr[nt] = *(const bf16x8*)&Bs[((TN / 2) * wn + 16 * nt + lm) * 64 + rs];
#pragma unroll
      for (int mt = 0; mt < 4; ++mt)
#pragma unroll
        for (int nt = 0; nt < NT; ++nt)
          acc[mt][nt] = MFMA32(af[mt], bfr[nt], acc[mt][nt]);
    }
  }

#pragma unroll
  for (int nt = 0; nt < NT; ++nt) {
    int gc = n0 + (TN / 2) * wn + 16 * nt + lm;
    float bv = bias[gc];
    if (VSPLIT && gc >= 2 * Cz) {
      // V column -> transposed store: vTout[(b*1024 + dg)][s0..s0+3]
      const int dg = gc - 2 * Cz;
#pragma unroll
      for (int mt = 0; mt < 4; ++mt) {
        const int gr0 = m0 + 64 * wm + 16 * mt + 4 * lg;
        const int bb = gr0 >> 11, s0 = gr0 & 2047;
        ushort4 o = {f2bf(acc[mt][nt][0] + bv), f2bf(acc[mt][nt][1] + bv),
                     f2bf(acc[mt][nt][2] + bv), f2bf(acc[mt][nt][3] + bv)};
        *(ushort4*)(vTout + (((size_t)(bb * 1024 + dg)) << 11) + s0) = o;
      }
      continue;
    }
    float sc = (gc < qcols) ? qscale : 1.f;
#pragma unroll
    for (int mt = 0; mt < 4; ++mt) {
#pragma unroll
      for (int i = 0; i < 4; ++i) {
        int gr = m0 + 64 * wm + 16 * mt + 4 * lg + i;
        float v = (acc[mt][nt][i] + bv) * sc;
        if (OUT_BF16)
          ((u16*)Cout)[(size_t)gr * N + gc] = f2bf(v);
        else
          ((float*)Cout)[(size_t)gr * N + gc] = v;
      }
    }
  }
}

// ---------------- flash attention, MFMA bf16, m=0 softmax, S^T ----------------
// 1D grid 1024: x = qtp*32+bh (XCD-affine); balanced qt = qtp<16?qtp:47-qtp.
// Wave w owns Q-rows [64qt+16w,+16). S^T = K*Q^T; p = exp2(S^T) packed
// in-register as 16x16x16-MFMA A-frag (P never touches LDS). K and V staged
// with global_load_lds (w=16) into unpadded stride-64 LDS; conflicts killed
// by XOR swizzle on the GLOBAL address (seg_g = seg_l ^ (row&7)) -- legal
// since gl_lds global addrs are per-lane, LDS base wave-uniform (m104).
// Frag reads un-swizzle; K b128 and V b64 patterns are bank-minimal (free).
// Double-buffered, ONE barrier/stage; gl_lds for kt+1 issued right after the
// barrier. V comes from pre-transposed vT[d][s] (written by qkv GEMM).
__global__ __launch_bounds__(256) void attn_kernel(const u16* __restrict__ qkv,
                                                   const u16* __restrict__ vT,
                                                   u16* __restrict__ yb) {
  __shared__ __align__(16) u16 KsL[2][64 * 64];
  __shared__ __align__(16) u16 VtL[2][64 * 64];

  const int t = threadIdx.x;
  const int wave = t >> 6, lane = t & 63;
  const int lm = lane & 15, lg = lane >> 4;
  const int x = blockIdx.x;
  const int bh = x & 31, qtp = x >> 5;
  const int qt = (qtp < 16) ? qtp : 47 - qtp;  // CU-balanced map
  const int b = bh >> 4, h = bh & 15;
  const int q0 = qt * 64;
  const size_t rowstride = 3 * Cz;
  const u16* qbase = qkv + (size_t)b * Tz * rowstride + h * Dz;
  const u16* vTbh = vT + ((size_t)(b * Hz + h) * Dz) * Tz;  // [64][2048]

  // Q fragments: B-operand of the S^T MFMA (lane lm = q-col, elems = d)
  bf16x8 qf[2];
  {
    const u16* qrow = qbase + (size_t)(q0 + wave * 16 + lm) * rowstride + (lg << 3);
    qf[0] = *(const bf16x8*)qrow;
    qf[1] = *(const bf16x8*)(qrow + 32);
  }

  float psum = 0.f;  // l for q = 16*wave + lm (partial over this lane's s)
  f32x4 Oa[4];       // Oa[dt][r] = O[q=16w+4lg+r][d=16dt+lm]
#pragma unroll
  for (int i = 0; i < 4; ++i)
#pragma unroll
    for (int j = 0; j < 4; ++j) Oa[i][j] = 0.f;

  // staging: wave w stages rows [16w,16w+16) of both K and V tiles.
  // lane i -> row +(i>>3), LDS seg i&7 holding GLOBAL seg (i&7)^(i>>3).
  const int srow = lane >> 3;              // 0..7
  const int sgl = ((lane & 7) ^ srow) * 8; // global col offset (swizzled)
  const u16* kstg = qbase + Cz + (size_t)(16 * wave + srow) * rowstride + sgl;
  const u16* vstg = vTbh + (size_t)(16 * wave + srow) * Tz + sgl;

  auto stage_issue = [&](int kt, int buf) {
#pragma unroll
    for (int c2 = 0; c2 < 2; ++c2) {
      gl_lds16(kstg + (size_t)(8 * c2) * rowstride + (size_t)(64 * kt) * rowstride,
               &KsL[buf][(16 * wave + 8 * c2) * 64]);
      gl_lds16(vstg + (size_t)(8 * c2) * Tz + 64 * kt,
               &VtL[buf][(16 * wave + 8 * c2) * 64]);
    }
  };

  stage_issue(0, 0);  // prologue; first barrier drains it

  for (int kt = 0; kt <= qt; ++kt) {
    __syncthreads();  // buf(kt&1) loads drained; prior readers of other buf done
    const int cb = kt & 1;
    if (kt + 1 <= qt) stage_issue(kt + 1, 1 - cb);

    // ---- S^T = K Q^T (pre-scaled): lane gets s=16c+4lg+r, q=16w+lm ----
    f32x4 S[4];
#pragma unroll
    for (int c = 0; c < 4; ++c) {
      const int rb = (16 * c + lm) * 64;
      bf16x8 k0 = *(const bf16x8*)&KsL[cb][rb + ((lg ^ (lm & 7)) << 3)];
      bf16x8 k1 = *(const bf16x8*)&KsL[cb][rb + (((lg + 4) ^ (lm & 7)) << 3)];
      f32x4 s;
#pragma unroll
      for (int i = 0; i < 4; ++i) s[i] = 0.f;
      s = MFMA32(k0, qf[0], s);
      s = MFMA32(k1, qf[1], s);
      S[c] = s;
    }

    // ---- p = exp2(S^T), diag mask, accumulate l, pack A-frags in-reg ----
    const bool diag = (kt == qt);
    const int qloc = 16 * wave + lm;
    bf16x4 pf[4];
#pragma unroll
    for (int c = 0; c < 4; ++c) {
#pragma unroll
      for (int r = 0; r < 4; ++r) {
        float p = fexp2(S[c][r]);
        if (diag && (c * 16 + 4 * lg + r) > qloc) p = 0.f;
        psum += p;
        pf[c][r] = (short)f2bf(p);
      }
    }

    // ---- O += P V: K=16 MFMAs, A=pf (registers), B from VtL[d][s] ----
#pragma unroll
    for (int dt = 0; dt < 4; ++dt) {
      const int rb = (16 * dt + lm) * 64;
#pragma unroll
      for (int c = 0; c < 4; ++c) {
        const int off = (((2 * c + (lg >> 1)) ^ (lm & 7)) << 3) + 4 * (lg & 1);
        bf16x4 vfr = *(const bf16x4*)&VtL[cb][rb + off];
        Oa[dt] = mfma16(pf[c], vfr, Oa[dt]);
      }
    }
  }

  // ---- epilogue: l-reduce over lg, redistribute inv, bounce via KsL[0] ----
  float s = psum;
  s += __shfl_xor(s, 16);
  s += __shfl_xor(s, 32);
  const float linv = 1.f / s;  // l(q=16w+lm), valid at all lg
  float invq[4];
#pragma unroll
  for (int r = 0; r < 4; ++r)
    invq[r] = __shfl(linv, 20 * lg + r);  // lane with lm = 4lg+r (same lg)
  __syncthreads();  // all KsL/VtL readers done; reuse KsL[0] as store bounce
#pragma unroll
  for (int dt = 0; dt < 4; ++dt)
#pragma unroll
    for (int r = 0; r < 4; ++r)
      KsL[0][(16 * wave + 4 * lg + r) * 64 + 16 * dt + lm] =
          f2bf(Oa[dt][r] * invq[r]);
  __syncthreads();
  {
    const int row = lane >> 2, seg = lane & 3;
    const uint4* src = (const uint4*)&KsL[0][(16 * wave + row) * 64 + seg * 16];
    uint4 v0 = src[0];
    uint4 v1 = src[1];
    u16* dst = yb + (size_t)(b * Tz + q0 + 16 * wave + row) * Cz + h * Dz + seg * 16;
    *(uint4*)dst = v0;
    *(uint4*)(dst + 8) = v1;
  }
}

extern "C" void kernel_launch(void* const* d_in, const int* in_sizes, int n_in,
                              void* d_out, int out_size, void* d_ws, size_t ws_size,
                              hipStream_t stream) {
  const float* x      = (const float*)d_in[0];
  const float* w_attn = (const float*)d_in[1];
  const float* b_attn = (const float*)d_in[2];
  const float* w_proj = (const float*)d_in[3];
  const float* b_proj = (const float*)d_in[4];

  char* ws = (char*)d_ws;
  u16* xb   = (u16*)(ws);                        //  8 MB: x bf16 [4096,1024]
  u16* waT  = (u16*)(ws + (8ull << 20));         //  6 MB: w_attn^T bf16 [3072,1024]
  u16* wpT  = (u16*)(ws + (14ull << 20));        //  2 MB: w_proj^T bf16 [1024,1024]
  u16* qkvb = (u16*)(ws + (16ull << 20));        // 24 MB: qkv bf16 (q pre-scaled; V cols unused)
  u16* yb   = (u16*)(ws + (40ull << 20));        //  8 MB: y bf16 [4096,1024]
  u16* vTt  = (u16*)(ws + (48ull << 20));        //  8 MB: V^T bf16 [2*16*64][2048]

  const int M = Bz * Tz;  // 4096

  prep_kernel<<<NCAST + NTA + 1024, 256, 0, stream>>>(x, w_attn, w_proj, xb, waT, wpT);
  gemm_bt<true, 96, true><<<dim3(3 * Cz / 96, M / 128), 256, 0, stream>>>(
      xb, waT, b_attn, qkvb, vTt, M, 3 * Cz, Cz, Cz, QSCALE);
  attn_kernel<<<1024, 256, 0, stream>>>(qkvb, vTt, yb);
  gemm_bt<false, 64, false><<<dim3(Cz / 64, M / 128), 256, 0, stream>>>(
      yb, wpT, b_proj, d_out, nullptr, M, Cz, Cz, 0, 1.f);
}

// Round 7
// 168.978 us; speedup vs baseline: 1.0660x; 1.0326x over previous
//
#include <hip/hip_runtime.h>

// Causal self-attention fwd: B=2,T=2048,C=1024,H=16,D=64, scale=0.1/sqrt(D)
// prep (cast x + transpose weights); qkv GEMM 128x128 BK=64 (global_load_lds,
// XOR seg swizzle, q pre-scaled by SCALE*log2e, V written PRE-TRANSPOSED to
// vT[d][s]); flash attn (S^T = K*Q^T, P in registers as 16x16x16-MFMA
// A-frags; K AND V staged via global_load_lds w/ global-side XOR swizzle --
// zero DS-write staging; double-buffered, 1 barrier/stage; m=0 softmax;
// XCD-affine CU-balanced grid); proj GEMM 128x64.
// SESSION LEDGER (R0=170.6us baseline, all deviations measured WORSE):
//   R2-R4: 256^2 8-phase qkv x3 variants -> 47/41/47us (vs 40) -- closed.
//   R5: proj TN=128 (1 block/CU) -> +9.5us -- closed.
//   R6: qkv TN=96 (4 blocks/CU but worse MFMA/byte) -> +4us -- closed.
// This file is the exact R0 configuration (proven optimum of this family).

#define Bz 2
#define Tz 2048
#define Cz 1024
#define Hz 16
#define Dz 64
// SCALE * log2(e): q pre-scaled so attn does p = exp2(S) directly
#define QSCALE 0.01803368801111437f

typedef unsigned short u16;
typedef short bf16x4 __attribute__((ext_vector_type(4)));
typedef short bf16x8 __attribute__((ext_vector_type(8)));
typedef float f32x4 __attribute__((ext_vector_type(4)));

#define MFMA32(A, B, C) __builtin_amdgcn_mfma_f32_16x16x32_bf16(A, B, C, 0, 0, 0)

// K=16 bf16 MFMA. Guard with __HIP_DEVICE_COMPILE__ (R8 lesson: __has_builtin
// is unreliable for aux-target builtins in the host pass).
__device__ inline f32x4 mfma16(bf16x4 a, bf16x4 b, f32x4 c) {
#if defined(__HIP_DEVICE_COMPILE__)
  return __builtin_amdgcn_mfma_f32_16x16x16bf16_1k(a, b, c, 0, 0, 0);
#else
  return c;  // host pass placeholder, never executed
#endif
}

__device__ inline u16 f2bf(float f) {  // round-half-up: 2 VALU, <=0.5 ulp
  return (u16)((__float_as_uint(f) + 0x8000u) >> 16);
}

__device__ inline float fexp2(float x) {  // raw v_exp_f32 (R6-proven guard)
#if __has_builtin(__builtin_amdgcn_exp2f)
  return __builtin_amdgcn_exp2f(x);
#else
  return exp2f(x);
#endif
}

__device__ inline void gl_lds16(const u16* g, u16* l) {
  __builtin_amdgcn_global_load_lds(
      (const __attribute__((address_space(1))) void*)g,
      (__attribute__((address_space(3))) void*)l, 16, 0, 0);
}

// ------------- prep: cast x->bf16 + transpose/cast both weights -------------
#define NCAST 4096   // (4096*1024/4)/256
#define NTA   3072   // (3072/32)*(1024/32)
__global__ __launch_bounds__(256) void prep_kernel(const float* __restrict__ x,
                                                   const float* __restrict__ wa,
                                                   const float* __restrict__ wp,
                                                   u16* __restrict__ xb,
                                                   u16* __restrict__ waT,
                                                   u16* __restrict__ wpT) {
  const int bx = blockIdx.x, t = threadIdx.x;
  if (bx < NCAST) {
    int i = bx * 256 + t;
    float4 v = ((const float4*)x)[i];
    ushort4 o = {f2bf(v.x), f2bf(v.y), f2bf(v.z), f2bf(v.w)};
    ((ushort4*)xb)[i] = o;
    return;
  }
  __shared__ float tile[32][33];
  const float* W;
  u16* WT;
  int N, idx;
  if (bx < NCAST + NTA) {
    W = wa; WT = waT; N = 3 * Cz; idx = bx - NCAST;
  } else {
    W = wp; WT = wpT; N = Cz; idx = bx - NCAST - NTA;
  }
  const int n0 = (idx % (N / 32)) * 32, k0 = (idx / (N / 32)) * 32;
  const int tx = t & 31, ty = t >> 5;  // (32, 8)
#pragma unroll
  for (int i = 0; i < 4; ++i)
    tile[ty + 8 * i][tx] = W[(size_t)(k0 + ty + 8 * i) * N + n0 + tx];
  __syncthreads();
#pragma unroll
  for (int i = 0; i < 4; ++i)
    WT[(size_t)(n0 + ty + 8 * i) * Cz + k0 + tx] = f2bf(tile[tx][ty + 8 * i]);
}

// ---------- C[M][N] = A[M][K]*BT[N][K]^T + bias; 128xTN tile, BK=64 ----------
// VSPLIT: cols >= 2C are V -- written transposed to vTout[(b*1024 + (gc-2C))]
// [s] as ushort4 (lane's 4 consecutive s), skipping Cout.
template <bool OUT_BF16, int TN, bool VSPLIT>
__global__ __launch_bounds__(256) void gemm_bt(const u16* __restrict__ A,
                                               const u16* __restrict__ BT,
                                               const float* __restrict__ bias,
                                               void* __restrict__ Cout,
                                               u16* __restrict__ vTout,
                                               int M, int N, int K,
                                               int qcols, float qscale) {
  __shared__ __align__(16) u16 As[128 * 64];
  __shared__ __align__(16) u16 Bs[TN * 64];
  constexpr int NT = TN / 32;
  const int t = threadIdx.x;
  const int wave = t >> 6, lane = t & 63;
  const int lm = lane & 15, lg = lane >> 4;
  const int wm = wave >> 1, wn = wave & 1;
  const int m0 = blockIdx.y * 128, n0 = blockIdx.x * TN;

  const int lrow = lane >> 3;                 // 0..7
  const int gseg = (lane & 7) ^ lrow;         // global col-seg (XOR swizzle)
  const size_t a_base = (size_t)(m0 + 32 * wave + lrow) * K + gseg * 8;
  u16* const a_lds = &As[(32 * wave) * 64];
  const size_t b_base = (size_t)(n0 + (TN / 4) * wave + lrow) * K + gseg * 8;
  u16* const b_lds = &Bs[((TN / 4) * wave) * 64];

  f32x4 acc[4][NT];
#pragma unroll
  for (int mt = 0; mt < 4; ++mt)
#pragma unroll
    for (int nt = 0; nt < NT; ++nt)
#pragma unroll
      for (int i = 0; i < 4; ++i) acc[mt][nt][i] = 0.f;

  for (int k0 = 0; k0 < K; k0 += 64) {
    __syncthreads();
#pragma unroll
    for (int i = 0; i < 4; ++i)
      gl_lds16(A + a_base + (size_t)(8 * i) * K + k0, a_lds + i * 8 * 64);
#pragma unroll
    for (int i = 0; i < NT; ++i)
      gl_lds16(BT + b_base + (size_t)(8 * i) * K + k0, b_lds + i * 8 * 64);
    __syncthreads();

#pragma unroll
    for (int h = 0; h < 2; ++h) {
      const int rs = ((lg + 4 * h) ^ (lm & 7)) * 8;
      bf16x8 af[4], bfr[NT];
#pragma unroll
      for (int mt = 0; mt < 4; ++mt)
        af[mt] = *(const bf16x8*)&As[(64 * wm + 16 * mt + lm) * 64 + rs];
#pragma unroll
      for (int nt = 0; nt < NT; ++nt)
        bfr[nt] = *(const bf16x8*)&Bs[((TN / 2) * wn + 16 * nt + lm) * 64 + rs];
#pragma unroll
      for (int mt = 0; mt < 4; ++mt)
#pragma unroll
        for (int nt = 0; nt < NT; ++nt)
          acc[mt][nt] = MFMA32(af[mt], bfr[nt], acc[mt][nt]);
    }
  }

#pragma unroll
  for (int nt = 0; nt < NT; ++nt) {
    int gc = n0 + (TN / 2) * wn + 16 * nt + lm;
    float bv = bias[gc];
    if (VSPLIT && gc >= 2 * Cz) {
      // V column -> transposed store: vTout[(b*1024 + dg)][s0..s0+3]
      const int dg = gc - 2 * Cz;
#pragma unroll
      for (int mt = 0; mt < 4; ++mt) {
        const int gr0 = m0 + 64 * wm + 16 * mt + 4 * lg;
        const int bb = gr0 >> 11, s0 = gr0 & 2047;
        ushort4 o = {f2bf(acc[mt][nt][0] + bv), f2bf(acc[mt][nt][1] + bv),
                     f2bf(acc[mt][nt][2] + bv), f2bf(acc[mt][nt][3] + bv)};
        *(ushort4*)(vTout + (((size_t)(bb * 1024 + dg)) << 11) + s0) = o;
      }
      continue;
    }
    float sc = (gc < qcols) ? qscale : 1.f;
#pragma unroll
    for (int mt = 0; mt < 4; ++mt) {
#pragma unroll
      for (int i = 0; i < 4; ++i) {
        int gr = m0 + 64 * wm + 16 * mt + 4 * lg + i;
        float v = (acc[mt][nt][i] + bv) * sc;
        if (OUT_BF16)
          ((u16*)Cout)[(size_t)gr * N + gc] = f2bf(v);
        else
          ((float*)Cout)[(size_t)gr * N + gc] = v;
      }
    }
  }
}

// ---------------- flash attention, MFMA bf16, m=0 softmax, S^T ----------------
// 1D grid 1024: x = qtp*32+bh (XCD-affine); balanced qt = qtp<16?qtp:47-qtp.
// Wave w owns Q-rows [64qt+16w,+16). S^T = K*Q^T; p = exp2(S^T) packed
// in-register as 16x16x16-MFMA A-frag (P never touches LDS). K and V staged
// with global_load_lds (w=16) into unpadded stride-64 LDS; conflicts killed
// by XOR swizzle on the GLOBAL address (seg_g = seg_l ^ (row&7)) -- legal
// since gl_lds global addrs are per-lane, LDS base wave-uniform (m104).
// Frag reads un-swizzle; K b128 and V b64 patterns are bank-minimal (free).
// Double-buffered, ONE barrier/stage; gl_lds for kt+1 issued right after the
// barrier. V comes from pre-transposed vT[d][s] (written by qkv GEMM).
__global__ __launch_bounds__(256) void attn_kernel(const u16* __restrict__ qkv,
                                                   const u16* __restrict__ vT,
                                                   u16* __restrict__ yb) {
  __shared__ __align__(16) u16 KsL[2][64 * 64];
  __shared__ __align__(16) u16 VtL[2][64 * 64];

  const int t = threadIdx.x;
  const int wave = t >> 6, lane = t & 63;
  const int lm = lane & 15, lg = lane >> 4;
  const int x = blockIdx.x;
  const int bh = x & 31, qtp = x >> 5;
  const int qt = (qtp < 16) ? qtp : 47 - qtp;  // CU-balanced map
  const int b = bh >> 4, h = bh & 15;
  const int q0 = qt * 64;
  const size_t rowstride = 3 * Cz;
  const u16* qbase = qkv + (size_t)b * Tz * rowstride + h * Dz;
  const u16* vTbh = vT + ((size_t)(b * Hz + h) * Dz) * Tz;  // [64][2048]

  // Q fragments: B-operand of the S^T MFMA (lane lm = q-col, elems = d)
  bf16x8 qf[2];
  {
    const u16* qrow = qbase + (size_t)(q0 + wave * 16 + lm) * rowstride + (lg << 3);
    qf[0] = *(const bf16x8*)qrow;
    qf[1] = *(const bf16x8*)(qrow + 32);
  }

  float psum = 0.f;  // l for q = 16*wave + lm (partial over this lane's s)
  f32x4 Oa[4];       // Oa[dt][r] = O[q=16w+4lg+r][d=16dt+lm]
#pragma unroll
  for (int i = 0; i < 4; ++i)
#pragma unroll
    for (int j = 0; j < 4; ++j) Oa[i][j] = 0.f;

  // staging: wave w stages rows [16w,16w+16) of both K and V tiles.
  // lane i -> row +(i>>3), LDS seg i&7 holding GLOBAL seg (i&7)^(i>>3).
  const int srow = lane >> 3;              // 0..7
  const int sgl = ((lane & 7) ^ srow) * 8; // global col offset (swizzled)
  const u16* kstg = qbase + Cz + (size_t)(16 * wave + srow) * rowstride + sgl;
  const u16* vstg = vTbh + (size_t)(16 * wave + srow) * Tz + sgl;

  auto stage_issue = [&](int kt, int buf) {
#pragma unroll
    for (int c2 = 0; c2 < 2; ++c2) {
      gl_lds16(kstg + (size_t)(8 * c2) * rowstride + (size_t)(64 * kt) * rowstride,
               &KsL[buf][(16 * wave + 8 * c2) * 64]);
      gl_lds16(vstg + (size_t)(8 * c2) * Tz + 64 * kt,
               &VtL[buf][(16 * wave + 8 * c2) * 64]);
    }
  };

  stage_issue(0, 0);  // prologue; first barrier drains it

  for (int kt = 0; kt <= qt; ++kt) {
    __syncthreads();  // buf(kt&1) loads drained; prior readers of other buf done
    const int cb = kt & 1;
    if (kt + 1 <= qt) stage_issue(kt + 1, 1 - cb);

    // ---- S^T = K Q^T (pre-scaled): lane gets s=16c+4lg+r, q=16w+lm ----
    f32x4 S[4];
#pragma unroll
    for (int c = 0; c < 4; ++c) {
      const int rb = (16 * c + lm) * 64;
      bf16x8 k0 = *(const bf16x8*)&KsL[cb][rb + ((lg ^ (lm & 7)) << 3)];
      bf16x8 k1 = *(const bf16x8*)&KsL[cb][rb + (((lg + 4) ^ (lm & 7)) << 3)];
      f32x4 s;
#pragma unroll
      for (int i = 0; i < 4; ++i) s[i] = 0.f;
      s = MFMA32(k0, qf[0], s);
      s = MFMA32(k1, qf[1], s);
      S[c] = s;
    }

    // ---- p = exp2(S^T), diag mask, accumulate l, pack A-frags in-reg ----
    const bool diag = (kt == qt);
    const int qloc = 16 * wave + lm;
    bf16x4 pf[4];
#pragma unroll
    for (int c = 0; c < 4; ++c) {
#pragma unroll
      for (int r = 0; r < 4; ++r) {
        float p = fexp2(S[c][r]);
        if (diag && (c * 16 + 4 * lg + r) > qloc) p = 0.f;
        psum += p;
        pf[c][r] = (short)f2bf(p);
      }
    }

    // ---- O += P V: K=16 MFMAs, A=pf (registers), B from VtL[d][s] ----
#pragma unroll
    for (int dt = 0; dt < 4; ++dt) {
      const int rb = (16 * dt + lm) * 64;
#pragma unroll
      for (int c = 0; c < 4; ++c) {
        const int off = (((2 * c + (lg >> 1)) ^ (lm & 7)) << 3) + 4 * (lg & 1);
        bf16x4 vfr = *(const bf16x4*)&VtL[cb][rb + off];
        Oa[dt] = mfma16(pf[c], vfr, Oa[dt]);
      }
    }
  }

  // ---- epilogue: l-reduce over lg, redistribute inv, bounce via KsL[0] ----
  float s = psum;
  s += __shfl_xor(s, 16);
  s += __shfl_xor(s, 32);
  const float linv = 1.f / s;  // l(q=16w+lm), valid at all lg
  float invq[4];
#pragma unroll
  for (int r = 0; r < 4; ++r)
    invq[r] = __shfl(linv, 20 * lg + r);  // lane with lm = 4lg+r (same lg)
  __syncthreads();  // all KsL/VtL readers done; reuse KsL[0] as store bounce
#pragma unroll
  for (int dt = 0; dt < 4; ++dt)
#pragma unroll
    for (int r = 0; r < 4; ++r)
      KsL[0][(16 * wave + 4 * lg + r) * 64 + 16 * dt + lm] =
          f2bf(Oa[dt][r] * invq[r]);
  __syncthreads();
  {
    const int row = lane >> 2, seg = lane & 3;
    const uint4* src = (const uint4*)&KsL[0][(16 * wave + row) * 64 + seg * 16];
    uint4 v0 = src[0];
    uint4 v1 = src[1];
    u16* dst = yb + (size_t)(b * Tz + q0 + 16 * wave + row) * Cz + h * Dz + seg * 16;
    *(uint4*)dst = v0;
    *(uint4*)(dst + 8) = v1;
  }
}

extern "C" void kernel_launch(void* const* d_in, const int* in_sizes, int n_in,
                              void* d_out, int out_size, void* d_ws, size_t ws_size,
                              hipStream_t stream) {
  const float* x      = (const float*)d_in[0];
  const float* w_attn = (const float*)d_in[1];
  const float* b_attn = (const float*)d_in[2];
  const float* w_proj = (const float*)d_in[3];
  const float* b_proj = (const float*)d_in[4];

  char* ws = (char*)d_ws;
  u16* xb   = (u16*)(ws);                        //  8 MB: x bf16 [4096,1024]
  u16* waT  = (u16*)(ws + (8ull << 20));         //  6 MB: w_attn^T bf16 [3072,1024]
  u16* wpT  = (u16*)(ws + (14ull << 20));        //  2 MB: w_proj^T bf16 [1024,1024]
  u16* qkvb = (u16*)(ws + (16ull << 20));        // 24 MB: qkv bf16 (q pre-scaled; V cols unused)
  u16* yb   = (u16*)(ws + (40ull << 20));        //  8 MB: y bf16 [4096,1024]
  u16* vTt  = (u16*)(ws + (48ull << 20));        //  8 MB: V^T bf16 [2*16*64][2048]

  const int M = Bz * Tz;  // 4096

  prep_kernel<<<NCAST + NTA + 1024, 256, 0, stream>>>(x, w_attn, w_proj, xb, waT, wpT);
  gemm_bt<true, 128, true><<<dim3(3 * Cz / 128, M / 128), 256, 0, stream>>>(
      xb, waT, b_attn, qkvb, vTt, M, 3 * Cz, Cz, Cz, QSCALE);
  attn_kernel<<<1024, 256, 0, stream>>>(qkvb, vTt, yb);
  gemm_bt<false, 64, false><<<dim3(Cz / 64, M / 128), 256, 0, stream>>>(
      yb, wpT, b_proj, d_out, nullptr, M, Cz, Cz, 0, 1.f);
}